// Round 13
// baseline (3670.183 us; speedup 1.0000x reference)
//
#include <hip/hip_runtime.h>
#include <cmath>

// Problem constants: B=256, T=256, D=128, E=32, F1=F2=512
#define B_   256
#define T_   256
#define D_   128
#define E_   32
#define F_   512
#define CB   16             // blocks per cluster
#define RC   16             // rows per cluster
#define ALPHA_F 0.1f
#define SCALE_F 0.31622776601683794f   // sqrt(0.1)
#define WS_SYNC_BYTES 4096

typedef float f32x4 __attribute__((ext_vector_type(4)));
typedef short s16x8 __attribute__((ext_vector_type(8)));
#define MFMA __builtin_amdgcn_mfma_f32_16x16x32_bf16

// ---- bf16 helpers (RNE) ----
__device__ __forceinline__ unsigned short f2bf(float f) {
    unsigned u = __float_as_uint(f);
    return (unsigned short)((u + 0x7FFFu + ((u >> 16) & 1u)) >> 16);
}
__device__ __forceinline__ unsigned pack2(float lo, float hi) {
    return (unsigned)f2bf(lo) | ((unsigned)f2bf(hi) << 16);
}

// ---- coherent-point primitives (sc0 sc1: write-through / L1-L2-bypass loads) ----
__device__ __forceinline__ void st_coh_u32(unsigned* p, unsigned v) {
    __hip_atomic_store(p, v, __ATOMIC_RELAXED, __HIP_MEMORY_SCOPE_AGENT);
}
__device__ __forceinline__ unsigned long long ld_coh_u64(const unsigned long long* p) {
    return __hip_atomic_load(p, __ATOMIC_RELAXED, __HIP_MEMORY_SCOPE_AGENT);
}

// A-fragment (8 bf16) from a frag exchange buffer at the coherent point.
// Layout: u32 index (S*64 + lane')*4 + piece; lane l gets row=l&15, k=32S+8*(l>>4)+e.
__device__ __forceinline__ s16x8 ld_frag(const unsigned* fb, int S, int l) {
    union { unsigned long long q[2]; s16x8 v; } u;
    const unsigned long long* p = (const unsigned long long*)(fb + (unsigned)(S * 64 + l) * 4u);
    u.q[0] = ld_coh_u64(p);
    u.q[1] = ld_coh_u64(p + 1);
    return u.v;
}

// A-fragment from 8 consecutive f32 in global memory (carry path)
__device__ __forceinline__ s16x8 frag_from_f32(const float* p) {
    float4 a = *(const float4*)p;
    float4 b = *(const float4*)(p + 4);
    union { unsigned q[4]; s16x8 v; } u;
    u.q[0] = pack2(a.x, a.y); u.q[1] = pack2(a.z, a.w);
    u.q[2] = pack2(b.x, b.y); u.q[3] = pack2(b.z, b.w);
    return u.v;
}

// B-fragment built directly from an f32 weight matrix (init only; R10-verified):
// elem e = W[(k0+e)*ldw + c]  (k0 = 32s + 8*(l>>4), c = 16*tile + (l&15))
__device__ __forceinline__ s16x8 frag_from_W(const float* W, int ldw, int k0, int c) {
    union { unsigned q[4]; s16x8 v; } u;
#pragma unroll
    for (int e2 = 0; e2 < 4; e2++)
        u.q[e2] = pack2(W[(size_t)(k0 + 2 * e2) * ldw + c],
                        W[(size_t)(k0 + 2 * e2 + 1) * ldw + c]);
    return u.v;
}

// ---- RMW-free cluster barrier (R12-proven) ----
__device__ __forceinline__ void cluster_barrier(unsigned* slots, int jb, unsigned g) {
    asm volatile("s_waitcnt vmcnt(0)" ::: "memory");
    __syncthreads();
    if (threadIdx.x == 0) {
        st_coh_u32(slots + jb, g);
        for (;;) {
            unsigned m = 0xFFFFFFFFu;
            const unsigned long long* p = (const unsigned long long*)slots;
#pragma unroll
            for (int i = 0; i < 8; i++) {
                unsigned long long v = ld_coh_u64(p + i);
                unsigned lo = (unsigned)v, hi = (unsigned)(v >> 32);
                m = m < lo ? m : lo;
                m = m < hi ? m : hi;
            }
            if (m >= g) break;
            __builtin_amdgcn_s_sleep(1);
        }
    }
    __syncthreads();
}

__global__ void __launch_bounds__(256, 1)
sde_scan_kernel(const float* __restrict__ carry, const float* __restrict__ x,
                const float* __restrict__ ext,   const float* __restrict__ noise,
                const float* __restrict__ W1,    const float* __restrict__ b1,
                const float* __restrict__ W2,    const float* __restrict__ b2,
                const float* __restrict__ W3,    const float* __restrict__ b3,
                float* __restrict__ out,         void* __restrict__ ws) {
    __shared__ alignas(16) short W2f[2 * 16 * 64 * 8];   // 32 KB  (own 32-col slice, R5 layout)
    __shared__ alignas(16) short W3f[16 * 64 * 8];       // 16 KB  (jb<8: cols 16jb..16jb+16)
    __shared__ alignas(16) short W1e[32 * 64 * 8];       // 32 KB  W1 kstep 4 (ext rows), ALL 512 cols
    __shared__ alignas(16) short h1loc[16 * 64 * 8];     // 16 KB  full h1 as A-frags (block-LOCAL)
    __shared__ alignas(16) f32x4 redb[4 * 64];           // 4 KB   G3 K-split combine
    __shared__ float b1s[F_];                            // 2 KB   (full: G1 computes all 512 cols)
    __shared__ float b2s[32], b3s[16];

    const int tid = threadIdx.x;
    const int bid = blockIdx.x;
    const int cl  = bid & 15;            // cluster
    const int jb  = bid >> 4;            // block-in-cluster 0..15
    const int rb  = cl * RC;             // global batch-row base
    const int cb  = jb * 32;             // F2 col base (G2 output slice)

    const int w  = tid >> 6;             // wave 0..3
    const int l  = tid & 63;
    const int lr = l & 15;               // frag row / col-within-16
    const int lh = l >> 4;               // k-octet / row-quad

    unsigned* slots = (unsigned*)ws + cl * 64;                                   // 16 slots/cluster
    unsigned* yf  = (unsigned*)((char*)ws + WS_SYNC_BYTES) + cl * 1024;          // 4 KB/cluster
    unsigned* h2f = (unsigned*)((char*)ws + WS_SYNC_BYTES + 65536) + cl * 4096;  // 16 KB/cluster

    float* yfin  = out;
    float* ys_o  = out + B_ * D_;
    float* mup_o = ys_o  + (size_t)B_ * T_ * D_;
    float* mus_o = mup_o + (size_t)B_ * T_ * D_;
    float* std_o = mus_o + (size_t)B_ * T_ * D_;

    // ---- one-time weight conversion ----
    // W2 slice (R5 verbatim layout [cg(2)][s(16)][lane][e])
    for (int e4 = tid; e4 < 512 * 8; e4 += 256) {
        int k = e4 >> 3, c0 = (e4 & 7) << 2;
        float4 v = *(const float4*)(W2 + k * F_ + cb + c0);
        float vv[4] = {v.x, v.y, v.z, v.w};
#pragma unroll
        for (int m = 0; m < 4; m++) {
            int c = c0 + m;
            W2f[((((c >> 4) * 16 + (k >> 5)) * 64) + (c & 15) + 16 * ((k >> 3) & 3)) * 8 + (k & 7)] =
                (short)f2bf(vv[m]);
        }
    }
    // W3 slice (jb<8, R5 verbatim)
    if (jb < 8) {
        for (int e4 = tid; e4 < 512 * 4; e4 += 256) {
            int k = e4 >> 2, c0 = (e4 & 3) << 2;
            float4 v = *(const float4*)(W3 + k * D_ + 16 * jb + c0);
            float vv[4] = {v.x, v.y, v.z, v.w};
#pragma unroll
            for (int m = 0; m < 4; m++) {
                int c = c0 + m;
                W3f[(((k >> 5) * 64) + c + 16 * ((k >> 3) & 3)) * 8 + (k & 7)] = (short)f2bf(vv[m]);
            }
        }
    }
    // W1 kstep 4 (rows 128..159), ALL 512 cols -> LDS [tile(32)][lane][e]
    for (int e4 = tid; e4 < 32 * 128; e4 += 256) {
        int kk = e4 >> 7;                 // 0..31 (k = 128+kk)
        int c0 = (e4 & 127) << 2;
        float4 v = *(const float4*)(W1 + (size_t)(128 + kk) * F_ + c0);
        float vv[4] = {v.x, v.y, v.z, v.w};
#pragma unroll
        for (int m = 0; m < 4; m++) {
            int c = c0 + m;
            W1e[((c >> 4) * 64 + (c & 15) + 16 * (kk >> 3)) * 8 + (kk & 7)] = (short)f2bf(vv[m]);
        }
    }
    for (int i = tid; i < F_; i += 256) b1s[i] = b1[i];
    if (tid < 32) b2s[tid] = b2[cb + tid];
    if (tid < 16) b3s[tid] = (jb < 8) ? b3[16 * jb + tid] : 0.f;

    // W1 ksteps 0..3 -> registers: wave w owns h1 col-tiles [8w, 8w+8)
    s16x8 w1r[8][4];
#pragma unroll
    for (int p = 0; p < 8; p++)
#pragma unroll
        for (int s = 0; s < 4; s++)
            w1r[p][s] = frag_from_W(W1, F_, 32 * s + 8 * lh, 16 * (8 * w + p) + lr);
    __syncthreads();

    // pointwise state (wave 0 of blocks jb<8): 4 rows (4lh+i) x col cg3
    const int cg3 = 16 * jb + lr;
    float y_reg[4] = {0.f, 0.f, 0.f, 0.f};
    if (jb < 8 && w == 0) {
#pragma unroll
        for (int i = 0; i < 4; i++) y_reg[i] = carry[(size_t)(rb + 4 * lh + i) * D_ + cg3];
    }

    // ext raw prefetch (one step ahead; removes HBM latency from G1 critical path)
    const size_t extbase = (size_t)(rb + lr) * T_ * E_ + 8 * lh;
    float4 ea = *(const float4*)(ext + extbase);
    float4 eb = *(const float4*)(ext + extbase + 4);

    const f32x4 z4 = {0.f, 0.f, 0.f, 0.f};
    unsigned gbar = 0;
    unsigned* h1u = (unsigned*)h1loc;

    for (int t = 0; t < T_; t++) {
        // build ext frag from prefetched raw (VALU only)
        s16x8 extf;
        {
            union { unsigned q[4]; s16x8 v; } u;
            u.q[0] = pack2(ea.x, ea.y); u.q[1] = pack2(ea.z, ea.w);
            u.q[2] = pack2(eb.x, eb.y); u.q[3] = pack2(eb.z, eb.w);
            extf = u.v;
        }

        // pointwise input prefetch (consumed in G3; overlaps G1+G2+bar)
        float x1p[4], x2p[4], nvp[4];
        if (jb < 8 && w == 0) {
#pragma unroll
            for (int i = 0; i < 4; i++) {
                size_t bt = (size_t)(rb + 4 * lh + i) * T_ + t;
                x1p[i] = x[bt * (2 * D_) + cg3];
                x2p[i] = x[bt * (2 * D_) + D_ + cg3];
                nvp[i] = noise[bt * D_ + cg3];
            }
        }

        // ============ G1 (ALL blocks, redundant): z(160) -> FULL h1, block-local ============
        // Wave w: col-tiles [8w, 8w+8), full K chained. Cheap GEMM -> replication buys
        // away the h1 all-gather hop entirely.
        {
            f32x4 acc[8];
#pragma unroll
            for (int p = 0; p < 8; p++) acc[p] = z4;
            s16x8 az[4];
            if (t == 0) {
#pragma unroll
                for (int s = 0; s < 4; s++)
                    az[s] = frag_from_f32(carry + (size_t)(rb + lr) * D_ + 32 * s + 8 * lh);
            } else {
#pragma unroll
                for (int s = 0; s < 4; s++) az[s] = ld_frag(yf, s, l);
            }
#pragma unroll
            for (int s = 0; s < 4; s++)
#pragma unroll
                for (int p = 0; p < 8; p++) acc[p] = MFMA(az[s], w1r[p][s], acc[p], 0, 0, 0);
#pragma unroll
            for (int p = 0; p < 8; p++)
                acc[p] = MFMA(extf, *(const s16x8*)&W1e[((8 * w + p) * 64 + l) * 8], acc[p], 0, 0, 0);

            // prefetch ext for t+1 (overlaps epilogue + barriers + G3)
            if (t + 1 < T_) {
                ea = *(const float4*)(ext + extbase + (size_t)(t + 1) * E_);
                eb = *(const float4*)(ext + extbase + (size_t)(t + 1) * E_ + 4);
            }

            // epilogue: bias+tanh, pack to A-frag layout in LOCAL LDS
#pragma unroll
            for (int p = 0; p < 8; p++) {
                const int tl  = 8 * w + p;
                const int ks2 = tl >> 1;                 // G2 kstep
                const int cl_ = 16 * (tl & 1) + lr;      // col within 32-col kstep group
                float bb = b1s[16 * tl + lr];
#pragma unroll
                for (int i = 0; i < 4; i++) {
                    float v = tanhf(acc[p][i] + bb);
                    float pv = __shfl_xor(v, 1);
                    if (!(l & 1))
                        h1u[(unsigned)(ks2 * 64 + 4 * lh + i + 16 * (cl_ >> 3)) * 4 + ((cl_ & 7) >> 1)] =
                            pack2(v, pv);
                }
            }
        }
        __syncthreads();                    // h1loc ready (block-local hop: ~0 cost)

        // ============ G2 (waves 0,1): h1(512, LDS) -> h2 cols [cb+16w, +16), full K ============
        if (w < 2) {
            f32x4 acc = z4;
#pragma unroll
            for (int s = 0; s < 16; s++) {
                s16x8 a = *(const s16x8*)&h1loc[(s * 64 + l) * 8];
                acc = MFMA(a, *(const s16x8*)&W2f[((w * 16 + s) * 64 + l) * 8], acc, 0, 0, 0);
            }
            const int cl_ = 16 * w + lr;
            float bb = b2s[cl_];
#pragma unroll
            for (int i = 0; i < 4; i++) {
                float v = tanhf(acc[i] + bb);
                float pv = __shfl_xor(v, 1);
                if (!(l & 1))
                    st_coh_u32(h2f + (unsigned)(jb * 64 + 4 * lh + i + 16 * (cl_ >> 3)) * 4
                                   + ((cl_ & 7) >> 1), pack2(v, pv));
            }
        }
        cluster_barrier(slots, jb, ++gbar);   // HOP 1: h2 complete cluster-wide

        // ========== G3 (blocks jb<8): h2(512) -> mu_phi cols [16jb..+16); K-split 4 ways ==========
        if (jb < 8) {
            s16x8 af[4];
#pragma unroll
            for (int q = 0; q < 4; q++) af[q] = ld_frag(h2f, 4 * w + q, l);
            f32x4 acc = z4;
#pragma unroll
            for (int q = 0; q < 4; q++)
                acc = MFMA(af[q], *(const s16x8*)&W3f[((4 * w + q) * 64 + l) * 8], acc, 0, 0, 0);
            if (w != 0) redb[w * 64 + l] = acc;
            __syncthreads();
            if (w == 0) {
                f32x4 p1 = redb[1 * 64 + l];
                f32x4 p2 = redb[2 * 64 + l];
                f32x4 p3 = redb[3 * 64 + l];
                float bb = b3s[lr];
                float yn4[4];
#pragma unroll
                for (int i = 0; i < 4; i++) {
                    float mu_phi = acc[i] + p1[i] + p2[i] + p3[i] + bb;
                    int rg = rb + 4 * lh + i;
                    size_t bt = (size_t)rg * T_ + t;
                    float mu = (1.0f - ALPHA_F) * y_reg[i] + ALPHA_F * mu_phi + x1p[i];
                    float sp = (x2p[i] > 0.f) ? (x2p[i] + log1pf(expf(-x2p[i]))) : log1pf(expf(x2p[i]));
                    float sd = SCALE_F * sp;
                    float yn = mu + sd * nvp[i];
                    mup_o[bt * D_ + cg3] = mu_phi;
                    mus_o[bt * D_ + cg3] = mu;
                    std_o[bt * D_ + cg3] = sd;
                    ys_o [bt * D_ + cg3] = yn;
                    y_reg[i] = yn;
                    yn4[i] = yn;
                    if (t == T_ - 1) yfin[(size_t)rg * D_ + cg3] = yn;
                }
                // y-frag exchange for next step's G1 (k = 16jb + lr; R5-verbatim addressing)
#pragma unroll
                for (int i = 0; i < 4; i++) {
                    float pv = __shfl_xor(yn4[i], 1);
                    if (!(l & 1)) {
                        int k = 16 * jb + lr;   // even
                        unsigned addr = (unsigned)((k >> 5) * 64 + 4 * lh + i + 16 * ((k >> 3) & 3)) * 4
                                        + ((lr & 7) >> 1);
                        st_coh_u32(yf + addr, pack2(yn4[i], pv));
                    }
                }
            }
        }
        cluster_barrier(slots, jb, ++gbar);   // HOP 2: y complete cluster-wide
    }
}

extern "C" void kernel_launch(void* const* d_in, const int* in_sizes, int n_in,
                              void* d_out, int out_size, void* d_ws, size_t ws_size,
                              hipStream_t stream) {
    const float* carry = (const float*)d_in[0];
    const float* x     = (const float*)d_in[1];
    const float* ext   = (const float*)d_in[2];
    const float* noise = (const float*)d_in[3];
    const float* W1    = (const float*)d_in[4];
    const float* b1    = (const float*)d_in[5];
    const float* W2    = (const float*)d_in[6];
    const float* b2    = (const float*)d_in[7];
    const float* W3    = (const float*)d_in[8];
    const float* b3    = (const float*)d_in[9];
    float* out = (float*)d_out;
    void* ws   = d_ws;

    // Zero only the barrier slot region (generations are monotonic within a call).
    hipMemsetAsync(d_ws, 0, WS_SYNC_BYTES, stream);

    sde_scan_kernel<<<dim3(256), dim3(256), 0, stream>>>(
        carry, x, ext, noise, W1, b1, W2, b2, W3, b3, out, ws);
}

// Round 14
// 2594.528 us; speedup vs baseline: 1.4146x; 1.4146x over previous
//
#include <hip/hip_runtime.h>
#include <cmath>

// Problem constants: B=256, T=256, D=128, E=32, F1=F2=512
#define B_   256
#define T_   256
#define D_   128
#define E_   32
#define F_   512
#define CB   16             // blocks per cluster
#define RC   16             // rows per cluster
#define ALPHA_F 0.1f
#define SCALE_F 0.31622776601683794f   // sqrt(0.1)
#define WS_SYNC_BYTES 4096

typedef float f32x4 __attribute__((ext_vector_type(4)));
typedef short s16x8 __attribute__((ext_vector_type(8)));
#define MFMA __builtin_amdgcn_mfma_f32_16x16x32_bf16

// ---- bf16 helpers (RNE) ----
__device__ __forceinline__ unsigned short f2bf(float f) {
    unsigned u = __float_as_uint(f);
    return (unsigned short)((u + 0x7FFFu + ((u >> 16) & 1u)) >> 16);
}
__device__ __forceinline__ unsigned pack2(float lo, float hi) {
    return (unsigned)f2bf(lo) | ((unsigned)f2bf(hi) << 16);
}

// ---- coherent-point primitives (sc0 sc1: write-through / L1-L2-bypass loads) ----
__device__ __forceinline__ void st_coh_u32(unsigned* p, unsigned v) {
    __hip_atomic_store(p, v, __ATOMIC_RELAXED, __HIP_MEMORY_SCOPE_AGENT);
}
__device__ __forceinline__ unsigned long long ld_coh_u64(const unsigned long long* p) {
    return __hip_atomic_load(p, __ATOMIC_RELAXED, __HIP_MEMORY_SCOPE_AGENT);
}

// A-fragment (8 bf16) from a frag exchange buffer at the coherent point.
// Layout: u32 index (S*64 + lane')*4 + piece; lane l gets row=l&15, k=32S+8*(l>>4)+e.
__device__ __forceinline__ s16x8 ld_frag(const unsigned* fb, int S, int l) {
    union { unsigned long long q[2]; s16x8 v; } u;
    const unsigned long long* p = (const unsigned long long*)(fb + (unsigned)(S * 64 + l) * 4u);
    u.q[0] = ld_coh_u64(p);
    u.q[1] = ld_coh_u64(p + 1);
    return u.v;
}

// A-fragment from 8 consecutive f32 in global memory (carry / ext paths)
__device__ __forceinline__ s16x8 frag_from_f32(const float* p) {
    float4 a = *(const float4*)p;
    float4 b = *(const float4*)(p + 4);
    union { unsigned q[4]; s16x8 v; } u;
    u.q[0] = pack2(a.x, a.y); u.q[1] = pack2(a.z, a.w);
    u.q[2] = pack2(b.x, b.y); u.q[3] = pack2(b.z, b.w);
    return u.v;
}

// ---- RMW-free cluster barrier (R12-proven): slot store + min-poll ----
__device__ __forceinline__ void barrier_poll(const unsigned* slots, unsigned g) {
    for (;;) {
        unsigned m = 0xFFFFFFFFu;
        const unsigned long long* p = (const unsigned long long*)slots;
#pragma unroll
        for (int i = 0; i < 8; i++) {
            unsigned long long v = ld_coh_u64(p + i);
            unsigned lo = (unsigned)v, hi = (unsigned)(v >> 32);
            m = m < lo ? m : lo;
            m = m < hi ? m : hi;
        }
        if (m >= g) break;
        __builtin_amdgcn_s_sleep(1);
    }
}
__device__ __forceinline__ void cluster_barrier(unsigned* slots, int jb, unsigned g) {
    asm volatile("s_waitcnt vmcnt(0)" ::: "memory");
    __syncthreads();
    if (threadIdx.x == 0) {
        st_coh_u32(slots + jb, g);
        barrier_poll(slots, g);
    }
    __syncthreads();
}

__global__ void __launch_bounds__(256, 1)
sde_scan_kernel(const float* __restrict__ carry, const float* __restrict__ x,
                const float* __restrict__ ext,   const float* __restrict__ noise,
                const float* __restrict__ W1,    const float* __restrict__ b1,
                const float* __restrict__ W2,    const float* __restrict__ b2,
                const float* __restrict__ W3,    const float* __restrict__ b3,
                float* __restrict__ out,         void* __restrict__ ws) {
    // bf16 weight fragments, converted once. B-frag: lane l = (c&15) + 16*((k>>3)&3), elem = k&7.
    __shared__ short W1f[2 * 5 * 64 * 8];    // 10 KB  (col-groups g=2, ksteps s=5)
    __shared__ short W2f[2 * 16 * 64 * 8];   // 32 KB
    __shared__ short W3f[16 * 64 * 8];       // 16 KB  (blocks j<8 only; cols 16j..16j+16)
    __shared__ float redb[8 * 64 * 4];       // 8 KB   (G2/G3 K-split combine)
    __shared__ float b1s[32], b2s[32], b3s[16];

    const int tid = threadIdx.x;
    const int bid = blockIdx.x;
    const int cl  = bid & 15;            // cluster
    const int jb  = bid >> 4;            // block-in-cluster 0..15
    const int rb  = cl * RC;             // global batch-row base
    const int cb  = jb * 32;             // F1/F2 col base

    const int w  = tid >> 6;             // wave 0..3
    const int l  = tid & 63;             // lane
    const int lr = l & 15;               // frag row (batch row) / output col
    const int lh = l >> 4;               // k-octet / row-quad

    unsigned* slots = (unsigned*)ws + cl * 64;   // 16 slots, 256B stride per cluster
    unsigned* yf  = (unsigned*)((char*)ws + WS_SYNC_BYTES) + cl * 1024;                  // 4 KB/cluster
    unsigned* h1f = (unsigned*)((char*)ws + WS_SYNC_BYTES + 65536) + cl * 4096;          // 16 KB/cluster
    unsigned* h2f = (unsigned*)((char*)ws + WS_SYNC_BYTES + 65536 + 262144) + cl * 4096; // 16 KB/cluster

    float* yfin  = out;
    float* ys_o  = out + B_ * D_;
    float* mup_o = ys_o  + (size_t)B_ * T_ * D_;
    float* mus_o = mup_o + (size_t)B_ * T_ * D_;
    float* std_o = mus_o + (size_t)B_ * T_ * D_;

    // ---- one-time weight conversion f32 -> bf16 frag layout (R12 verbatim) ----
    for (int e4 = tid; e4 < 160 * 8; e4 += 256) {
        int k = e4 >> 3, c0 = (e4 & 7) << 2;
        float4 v = *(const float4*)(W1 + k * F_ + cb + c0);
        float vv[4] = {v.x, v.y, v.z, v.w};
#pragma unroll
        for (int m = 0; m < 4; m++) {
            int c = c0 + m;
            W1f[((((c >> 4) * 5 + (k >> 5)) * 64) + (c & 15) + 16 * ((k >> 3) & 3)) * 8 + (k & 7)] =
                (short)f2bf(vv[m]);
        }
    }
    for (int e4 = tid; e4 < 512 * 8; e4 += 256) {
        int k = e4 >> 3, c0 = (e4 & 7) << 2;
        float4 v = *(const float4*)(W2 + k * F_ + cb + c0);
        float vv[4] = {v.x, v.y, v.z, v.w};
#pragma unroll
        for (int m = 0; m < 4; m++) {
            int c = c0 + m;
            W2f[((((c >> 4) * 16 + (k >> 5)) * 64) + (c & 15) + 16 * ((k >> 3) & 3)) * 8 + (k & 7)] =
                (short)f2bf(vv[m]);
        }
    }
    if (jb < 8) {
        for (int e4 = tid; e4 < 512 * 4; e4 += 256) {
            int k = e4 >> 2, c0 = (e4 & 3) << 2;
            float4 v = *(const float4*)(W3 + k * D_ + 16 * jb + c0);
            float vv[4] = {v.x, v.y, v.z, v.w};
#pragma unroll
            for (int m = 0; m < 4; m++) {
                int c = c0 + m;
                W3f[(((k >> 5) * 64) + c + 16 * ((k >> 3) & 3)) * 8 + (k & 7)] = (short)f2bf(vv[m]);
            }
        }
    }
    if (tid < 32) { b1s[tid] = b1[cb + tid]; b2s[tid] = b2[cb + tid]; }
    if (tid < 16) { b3s[tid] = (jb < 8) ? b3[16 * jb + tid] : 0.f; }
    __syncthreads();

    // pointwise state (wave 0 of blocks jb<8): 4 rows (4*lh+i) x col cg3
    const int cg3 = 16 * jb + lr;
    float y_reg[4] = {0.f, 0.f, 0.f, 0.f};
    if (jb < 8 && w == 0) {
#pragma unroll
        for (int i = 0; i < 4; i++) y_reg[i] = carry[(size_t)(rb + 4 * lh + i) * D_ + cg3];
    }

    const f32x4 z4 = {0.f, 0.f, 0.f, 0.f};
    unsigned gbar = 0;

    for (int t = 0; t < T_; t++) {
        // prefetch pointwise inputs (hide under GEMMs)
        float x1p[4], x2p[4], nvp[4];
        if (jb < 8 && w == 0) {
#pragma unroll
            for (int i = 0; i < 4; i++) {
                size_t bt = (size_t)(rb + 4 * lh + i) * T_ + t;
                x1p[i] = x[bt * (2 * D_) + cg3];
                x2p[i] = x[bt * (2 * D_) + D_ + cg3];
                nvp[i] = noise[bt * D_ + cg3];
            }
        }

        // ====== GEMM1 (full-K per wave): z(160) -> h1 col-group w of [32jb..32jb+32) ======
        // w0 -> cols [32jb,32jb+16), w1 -> [32jb+16,32jb+32). 5 chained MFMA, no redb,
        // no syncthreads, no combine: shortest possible straggler chain for G1.
        if (w < 2) {
            // issue ext load first so it overlaps the yf frag loads
            s16x8 extf = frag_from_f32(ext + ((size_t)(rb + lr) * T_ + t) * E_ + 8 * lh);
            s16x8 az[4];
            if (t == 0) {
#pragma unroll
                for (int s = 0; s < 4; s++)
                    az[s] = frag_from_f32(carry + (size_t)(rb + lr) * D_ + 32 * s + 8 * lh);
            } else {
#pragma unroll
                for (int s = 0; s < 4; s++) az[s] = ld_frag(yf, s, l);
            }
            f32x4 acc = z4;
#pragma unroll
            for (int s = 0; s < 4; s++)
                acc = MFMA(az[s], *(const s16x8*)&W1f[((w * 5 + s) * 64 + l) * 8], acc, 0, 0, 0);
            acc = MFMA(extf, *(const s16x8*)&W1f[((w * 5 + 4) * 64 + l) * 8], acc, 0, 0, 0);

            const int cl_ = 16 * w + lr;
            float bb = b1s[cl_];
#pragma unroll
            for (int i = 0; i < 4; i++) {
                float v = tanhf(acc[i] + bb);
                float pv = __shfl_xor(v, 1);
                if (!(l & 1)) {
                    unsigned addr = (unsigned)(jb * 64 + 4 * lh + i + 16 * (cl_ >> 3)) * 4 + ((cl_ & 7) >> 1);
                    st_coh_u32(h1f + addr, pack2(v, pv));
                }
            }
        }
        cluster_barrier(slots, jb, ++gbar);

        // ================= GEMM2: h1(512) -> h2 cols [32jb..32jb+32) (R12 verbatim) =================
        {
            s16x8 af[4];
#pragma unroll
            for (int q = 0; q < 4; q++) af[q] = ld_frag(h1f, 4 * w + q, l);
            f32x4 acc0 = z4, acc1 = z4;
#pragma unroll
            for (int q = 0; q < 4; q++) {
                int s = 4 * w + q;
                s16x8 b0 = *(const s16x8*)&W2f[((0 * 16 + s) * 64 + l) * 8];
                s16x8 b1 = *(const s16x8*)&W2f[((1 * 16 + s) * 64 + l) * 8];
                acc0 = MFMA(af[q], b0, acc0, 0, 0, 0);
                acc1 = MFMA(af[q], b1, acc1, 0, 0, 0);
            }
            *(f32x4*)&redb[((w * 2 + 0) * 64 + l) * 4] = acc0;
            *(f32x4*)&redb[((w * 2 + 1) * 64 + l) * 4] = acc1;
        }
        __syncthreads();
        if (w < 2) {
            f32x4 s0 = *(const f32x4*)&redb[((0 * 2 + w) * 64 + l) * 4];
            f32x4 s1 = *(const f32x4*)&redb[((1 * 2 + w) * 64 + l) * 4];
            f32x4 s2 = *(const f32x4*)&redb[((2 * 2 + w) * 64 + l) * 4];
            f32x4 s3 = *(const f32x4*)&redb[((3 * 2 + w) * 64 + l) * 4];
            int cl_ = 16 * w + lr;
            float bb = b2s[cl_];
#pragma unroll
            for (int i = 0; i < 4; i++) {
                float v = tanhf(s0[i] + s1[i] + s2[i] + s3[i] + bb);
                float pv = __shfl_xor(v, 1);
                if (!(l & 1)) {
                    unsigned addr = (unsigned)(jb * 64 + 4 * lh + i + 16 * (cl_ >> 3)) * 4 + ((cl_ & 7) >> 1);
                    st_coh_u32(h2f + addr, pack2(v, pv));
                }
            }
        }
        cluster_barrier(slots, jb, ++gbar);

        // ========== GEMM3 (jb<8): h2(512) -> mu_phi cols [16jb..16jb+16) (R12 verbatim) ==========
        float mu_phi4[4], mu4[4], sd4[4], yn4[4];
        if (jb < 8) {
            s16x8 af[4];
#pragma unroll
            for (int q = 0; q < 4; q++) af[q] = ld_frag(h2f, 4 * w + q, l);
            f32x4 acc = z4;
#pragma unroll
            for (int q = 0; q < 4; q++) {
                s16x8 b0 = *(const s16x8*)&W3f[((4 * w + q) * 64 + l) * 8];
                acc = MFMA(af[q], b0, acc, 0, 0, 0);
            }
            if (w != 0) *(f32x4*)&redb[(w * 64 + l) * 4] = acc;
            __syncthreads();
            if (w == 0) {
                f32x4 p1 = *(const f32x4*)&redb[(1 * 64 + l) * 4];
                f32x4 p2 = *(const f32x4*)&redb[(2 * 64 + l) * 4];
                f32x4 p3 = *(const f32x4*)&redb[(3 * 64 + l) * 4];
                float bb = b3s[lr];
#pragma unroll
                for (int i = 0; i < 4; i++) {
                    float mu_phi = acc[i] + p1[i] + p2[i] + p3[i] + bb;
                    float mu = (1.0f - ALPHA_F) * y_reg[i] + ALPHA_F * mu_phi + x1p[i];
                    float sp = (x2p[i] > 0.f) ? (x2p[i] + log1pf(expf(-x2p[i]))) : log1pf(expf(x2p[i]));
                    float sd = SCALE_F * sp;
                    float yn = mu + sd * nvp[i];
                    mu_phi4[i] = mu_phi; mu4[i] = mu; sd4[i] = sd; yn4[i] = yn;
                    y_reg[i] = yn;
                }
                // y-frag exchange for next step's GEMM1 (k = 16*jb + lr) — MUST precede the drain
#pragma unroll
                for (int i = 0; i < 4; i++) {
                    float pv = __shfl_xor(yn4[i], 1);
                    if (!(l & 1)) {
                        int k = 16 * jb + lr;   // even
                        unsigned addr = (unsigned)((k >> 5) * 64 + 4 * lh + i + 16 * ((k >> 3) & 3)) * 4
                                        + ((lr & 7) >> 1);
                        st_coh_u32(yf + addr, pack2(yn4[i], pv));
                    }
                }
            }
        }

        // ---- split bar_y: drain yf -> publish -> (outputs issue under the poll) -> poll ----
        gbar++;
        asm volatile("s_waitcnt vmcnt(0)" ::: "memory");   // drains yf stores (outputs not yet issued)
        __syncthreads();
        if (tid == 0) st_coh_u32(slots + jb, gbar);
        if (jb < 8 && w == 0) {
            // HBM output stores hidden under the barrier poll; drained by next bar's vmcnt.
#pragma unroll
            for (int i = 0; i < 4; i++) {
                int rg = rb + 4 * lh + i;
                size_t bt = (size_t)rg * T_ + t;
                mup_o[bt * D_ + cg3] = mu_phi4[i];
                mus_o[bt * D_ + cg3] = mu4[i];
                std_o[bt * D_ + cg3] = sd4[i];
                ys_o [bt * D_ + cg3] = yn4[i];
                if (t == T_ - 1) yfin[(size_t)rg * D_ + cg3] = yn4[i];
            }
        }
        if (tid == 0) barrier_poll(slots, gbar);
        __syncthreads();
    }
}

extern "C" void kernel_launch(void* const* d_in, const int* in_sizes, int n_in,
                              void* d_out, int out_size, void* d_ws, size_t ws_size,
                              hipStream_t stream) {
    const float* carry = (const float*)d_in[0];
    const float* x     = (const float*)d_in[1];
    const float* ext   = (const float*)d_in[2];
    const float* noise = (const float*)d_in[3];
    const float* W1    = (const float*)d_in[4];
    const float* b1    = (const float*)d_in[5];
    const float* W2    = (const float*)d_in[6];
    const float* b2    = (const float*)d_in[7];
    const float* W3    = (const float*)d_in[8];
    const float* b3    = (const float*)d_in[9];
    float* out = (float*)d_out;
    void* ws   = d_ws;

    // Zero only the barrier slot region (generations are monotonic within a call).
    hipMemsetAsync(d_ws, 0, WS_SYNC_BYTES, stream);

    sde_scan_kernel<<<dim3(256), dim3(256), 0, stream>>>(
        carry, x, ext, noise, W1, b1, W2, b2, W3, b3, out, ws);
}